// Round 8
// baseline (275.164 us; speedup 1.0000x reference)
//
#include <hip/hip_runtime.h>
#include <hip/hip_bf16.h>
#include <stdint.h>

#define NROWS 16384            // 16*32*32 flattened rows
#define KCODES 8192
#define DIM 256
#define HW 1024                // 32*32
#define CHW (DIM*HW)           // 262144
#define IDX_OFF 4194304        // 16*256*32*32
#define LOSS_OFF 4210688       // IDX_OFF + 16384
#define TAU 1.2e-4f            // candidate margin: grid(3.05e-5) + 2*bf16 tail + safety

typedef unsigned long long u64;
typedef unsigned int u32;
typedef unsigned short ushort_t;

using frag = __attribute__((ext_vector_type(8))) short;   // 8 bf16 (4 VGPRs)
using accf = __attribute__((ext_vector_type(4))) float;   // 4 fp32 acc

__device__ __forceinline__ u32 forder(float f) {
    u32 u = __float_as_uint(f);
    return (u & 0x80000000u) ? ~u : (u | 0x80000000u);
}
__device__ __forceinline__ float unforder(u32 v) {
    u32 u = (v & 0x80000000u) ? (v ^ 0x80000000u) : ~v;
    return __uint_as_float(u);
}
__device__ __forceinline__ ushort_t bf16bits(float v) {
    __hip_bfloat16 t = __float2bfloat16(v);   // RNE
    return *reinterpret_cast<ushort_t*>(&t);
}
__device__ __forceinline__ float bflo(u32 u) { return __uint_as_float(u << 16); }
__device__ __forceinline__ float bfhi(u32 u) { return __uint_as_float(u & 0xFFFF0000u); }
__device__ __forceinline__ void async_cp16(const uint4* gp, uint4* lp) {
    __builtin_amdgcn_global_load_lds(
        (const __attribute__((address_space(1))) unsigned int*)gp,
        (__attribute__((address_space(3))) unsigned int*)lp, 16, 0, 0);
}

// max across each 16-lane DPP row, all on the VALU pipe (no DS traffic).
__device__ __forceinline__ float max_dpp16(float v) {
    int x;
    x = __builtin_amdgcn_update_dpp(__float_as_int(v), __float_as_int(v), 0xB1, 0xF, 0xF, true);
    v = fmaxf(v, __int_as_float(x));
    x = __builtin_amdgcn_update_dpp(__float_as_int(v), __float_as_int(v), 0x4E, 0xF, 0xF, true);
    v = fmaxf(v, __int_as_float(x));
    x = __builtin_amdgcn_update_dpp(__float_as_int(v), __float_as_int(v), 0x124, 0xF, 0xF, true);
    v = fmaxf(v, __int_as_float(x));
    x = __builtin_amdgcn_update_dpp(__float_as_int(v), __float_as_int(v), 0x128, 0xF, 0xF, true);
    v = fmaxf(v, __int_as_float(x));
    return v;
}

// EXACT scoring chain (bit-identical to all passing rounds): sequential k fp32
// fmaf on fp32 cb, fl32(rn - 2*dot), key = (ordered score, code); ties -> lowest.
__device__ __forceinline__ u64 exact_key(const float* __restrict__ cb,
                                         const float* __restrict__ fs,
                                         float rn_row, int code) {
    const float4* e4 = reinterpret_cast<const float4*>(&cb[(size_t)code << 8]);
    float acc = 0.0f;
    #pragma unroll 16
    for (int kk = 0; kk < 64; ++kk) {
        float4 ev = e4[kk];
        float4 fv = *reinterpret_cast<const float4*>(&fs[kk << 2]);
        acc = fmaf(fv.x, ev.x, acc);
        acc = fmaf(fv.y, ev.y, acc);
        acc = fmaf(fv.z, ev.z, acc);
        acc = fmaf(fv.w, ev.w, acc);
    }
    float s = __fadd_rn(rn_row, -2.0f * acc);
    return ((u64)forder(s) << 32) | (u64)code;
}

// ws layout (bytes):
//   keys   u64[16384]          @ 0        (131072)
//   rn     f32[16384]          @ 131072   (65536)
//   rowmin u32[16384]          @ 196608   (65536)
//   A_bf   u16[16384*256]      @ 262144   (8388608)  PLANE-MAJOR+SWIZZLED:
//          uint4 idx = g*131072 + row*8 + ((u&7)^(row&7)), g=k-group(64k), u=k/8
//   B_bf   u16[8192*256]       @ 8650752  (4194304)  uint4 idx = g*65536 + code*8 + slot,
//          slot = u ^ (code&7)
//   sbmin  f32[16384*256]      @ 12845056 (16777216) per (row, 32-code sub) approx min

// hs -> bf16 rows (plane-major swizzled) + exact numpy-pairwise rn + inits.
// Round-18 split (verified): two half-sum chains on separate 64-thread groups;
// per-chain adds, packing, swizzled stores, rn = fadd(hs0,hs1) bit-identical.
__global__ __launch_bounds__(128)
void convert_hs(const float* __restrict__ hs, ushort_t* __restrict__ Abf,
                float* __restrict__ rn, u32* __restrict__ rowmin,
                float* __restrict__ out) {
    __shared__ uint4 tile[2][64 * 17];   // per-half tile; stride 17: bank coverage
    __shared__ float hsx[2][64];
    const int t = threadIdx.x;
    const int tr = t & 63;               // row within block
    const int h = t >> 6;                // half 0/1 (channel groups 0-127 / 128-255)
    const int row0 = blockIdx.x * 64;
    const int row = row0 + tr;
    if (h == 0) {
        rowmin[row] = 0xFFFFFFFFu;
        if (row == 0) out[LOSS_OFF] = 0.0f;
    }
    const int b = row >> 10, hw = row & 1023;
    const float* p = hs + (size_t)b * CHW + hw;
    uint4* Abf4 = reinterpret_cast<uint4*>(Abf);

    float r[8];
    for (int i = 0; i < 128; i += 8) {
        ushort_t pk[8];
        #pragma unroll
        for (int j = 0; j < 8; ++j) {
            int c = h * 128 + i + j;
            float v = p[(size_t)c * HW];       // coalesced across each group's 64 lanes
            pk[j] = bf16bits(v);
            float sq = __fmul_rn(v, v);
            r[j] = (i == 0) ? sq : __fadd_rn(r[j], sq);
        }
        uint4 o;
        o.x = (u32)pk[0] | ((u32)pk[1] << 16);
        o.y = (u32)pk[2] | ((u32)pk[3] << 16);
        o.z = (u32)pk[4] | ((u32)pk[5] << 16);
        o.w = (u32)pk[6] | ((u32)pk[7] << 16);
        tile[h][tr * 17 + (i >> 3)] = o;
    }
    float halfsum = __fadd_rn(__fadd_rn(__fadd_rn(r[0], r[1]), __fadd_rn(r[2], r[3])),
                              __fadd_rn(__fadd_rn(r[4], r[5]), __fadd_rn(r[6], r[7])));
    hsx[h][tr] = halfsum;
    __syncthreads();

    // store pass: each group writes its own half's 16 uint4 k-slots.
    #pragma unroll
    for (int pass = 0; pass < 16; ++pass) {
        int rr = pass * 4 + (tr >> 4);
        int uh = tr & 15;
        uint4 v = tile[h][rr * 17 + uh];
        int orow = row0 + rr;
        int u = h * 16 + uh;                  // global uint4 k-slot 0..31
        int g = u >> 3;
        int slot = (u & 7) ^ (orow & 7);
        Abf4[(size_t)g * 131072 + (size_t)orow * 8 + slot] = v;
    }
    if (h == 0) rn[row] = __fadd_rn(hsx[0][tr], hsx[1][tr]);
}

// codebook -> bf16, plane-major swizzled. One thread per output uint4 (coalesced).
__global__ __launch_bounds__(256)
void convert_cb(const float* __restrict__ cb, ushort_t* __restrict__ Bbf) {
    int o = blockIdx.x * 256 + threadIdx.x;        // output uint4 idx, 262144 total
    int g = o >> 16;                               // 65536 uint4 per plane
    int rem = o & 65535;
    int code = rem >> 3;
    int slot = rem & 7;
    int u = slot ^ (code & 7);                     // source uint4-in-group
    const float4* src = reinterpret_cast<const float4*>(
        cb + (size_t)code * DIM + (size_t)(g * 8 + u) * 8);
    float4 v0 = src[0], v1 = src[1];
    uint4 out_v;
    out_v.x = (u32)bf16bits(v0.x) | ((u32)bf16bits(v0.y) << 16);
    out_v.y = (u32)bf16bits(v0.z) | ((u32)bf16bits(v0.w) << 16);
    out_v.z = (u32)bf16bits(v1.x) | ((u32)bf16bits(v1.y) << 16);
    out_v.w = (u32)bf16bits(v1.z) | ((u32)bf16bits(v1.w) << 16);
    reinterpret_cast<uint4*>(Bbf)[o] = out_v;
}

// Approx GEMM: round-17 structure VERBATIM (best measured: 97.8us).
//   A+B via LDS, 2-phase double-buffer, single barrier per K-step, 16 waves
//   (wave tile 64x64, acc[4][4]), DPP epilogue. r18's coarse wave-group phase
//   split regressed (105.6us) exactly per m196's "coarse split without fine
//   interleave hurts" — reverted.
__global__ __launch_bounds__(1024, 4)
void mfma_approx(const ushort_t* __restrict__ Abf, const ushort_t* __restrict__ Bbf,
                 float* __restrict__ sbmin, u32* __restrict__ rowmin) {
    __shared__ uint4 As4[2][2048];   // 2 x 32 KB: [row 0..255][slot 0..7]
    __shared__ uint4 Bs4[2][2048];   // 2 x 32 KB: [code 0..255][slot 0..7]

    const int tid = threadIdx.x;
    const int n0 = blockIdx.x << 8;     // 256 rows per block
    const int c0 = blockIdx.y << 8;     // 256 codes per block
    const int w = tid >> 6, L = tid & 63;
    const int wr = w & 3, wc = w >> 2;  // wave tile: rows 64*wr, codes 64*wc
    const int m = L & 15, q = L >> 4;
    const uint4* gA = reinterpret_cast<const uint4*>(Abf);
    const uint4* gB = reinterpret_cast<const uint4*>(Bbf);

    accf acc[4][4];
    #pragma unroll
    for (int rt = 0; rt < 4; ++rt)
        #pragma unroll
        for (int ct = 0; ct < 4; ++ct) acc[rt][ct] = (accf){0.f, 0.f, 0.f, 0.f};

#define STAGE(buf, gg) do {                                                   \
    _Pragma("unroll")                                                         \
    for (int r_ = 0; r_ < 2; ++r_) {                                          \
        int j_ = (r_ << 10) + tid;                                            \
        async_cp16(gA + ((size_t)(gg) * 131072 + (size_t)n0 * 8 + j_),        \
                   &As4[buf][j_]);                                            \
    }                                                                         \
    _Pragma("unroll")                                                         \
    for (int r_ = 0; r_ < 2; ++r_) {                                          \
        int j_ = (r_ << 10) + tid;                                            \
        async_cp16(gB + ((size_t)(gg) * 65536 + (size_t)c0 * 8 + j_),         \
                   &Bs4[buf][j_]);                                            \
    }                                                                         \
} while (0)

    STAGE(0, 0);
    __syncthreads();                    // drains prologue stage (vmcnt 0) + barrier

    #pragma unroll
    for (int g = 0; g < 4; ++g) {       // kc = 64*g
        const int cur = g & 1;
        if (g < 3) STAGE(cur ^ 1, g + 1);   // issue next tile, in flight across compute
        #pragma unroll
        for (int ks = 0; ks < 2; ++ks) {
            const int us = ((ks << 2) + q) ^ (m & 7);
            frag a[4];
            #pragma unroll
            for (int rt = 0; rt < 4; ++rt)
                a[rt] = *reinterpret_cast<const frag*>(
                    &As4[cur][((wr << 6) + (rt << 4) + m) * 8 + us]);
            #pragma unroll
            for (int ct = 0; ct < 4; ++ct) {
                frag bfr = *reinterpret_cast<const frag*>(
                    &Bs4[cur][((wc << 6) + (ct << 4) + m) * 8 + us]);
                #pragma unroll
                for (int rt = 0; rt < 4; ++rt)
                    acc[rt][ct] = __builtin_amdgcn_mfma_f32_16x16x32_bf16(a[rt], bfr, acc[rt][ct], 0, 0, 0);
            }
        }
        if (g < 3) __syncthreads();     // drains this iter's STAGE + WAR barrier
    }
#undef STAGE

    // Epilogue: subblock (32-code) mins + row min via DPP (VALU pipe only).
    // Wave covers 64 codes = 2 subblocks: p in {0,1}, ct pairs {0,1},{2,3}.
    const int cbase = (blockIdx.y << 3) + (wc << 1);
    #pragma unroll
    for (int rt = 0; rt < 4; ++rt) {
        #pragma unroll
        for (int reg = 0; reg < 4; ++reg) {
            float mx[2];
            #pragma unroll
            for (int p = 0; p < 2; ++p)
                mx[p] = fmaxf(acc[rt][2 * p][reg], acc[rt][2 * p + 1][reg]);
            #pragma unroll
            for (int p = 0; p < 2; ++p) mx[p] = max_dpp16(mx[p]);
            if (m == 0) {   // lanes 0,16,32,48 (one per 16-lane row)
                int row = n0 + (wr << 6) + (rt << 4) + (q << 2) + reg;
                float mn[2];
                #pragma unroll
                for (int p = 0; p < 2; ++p) {
                    mn[p] = -2.0f * mx[p];
                    sbmin[(size_t)row * 256 + cbase + p] = mn[p];
                }
                float m2 = fminf(mn[0], mn[1]);
                atomicMin(&rowmin[row], forder(m2));
            }
        }
    }
}

// Exact rescore (round-14 wave-cooperative filter + round-19 pipelined Bbf
// prefetch): 8 lanes per code, fs register-staged; pass it+1's 4 uint4 loads
// issued during pass it's compute (identical loads/ops, reordered only).
// Survivors -> LDS list -> EXACT chain (bit-identical).
__global__ __launch_bounds__(64, 4)
void rescore(const float* __restrict__ hs, const float* __restrict__ cb,
             const float* __restrict__ rn, const float* __restrict__ sbmin,
             const u32* __restrict__ rowmin, u64* __restrict__ keys,
             const ushort_t* __restrict__ Bbf) {
    __shared__ __align__(16) float fs[256];
    __shared__ int list[256];
    __shared__ int surv[512];
    __shared__ int cnt, cnt2;
    const int bid = blockIdx.x;
    const int row = ((bid & 7) << 11) + (bid >> 3);   // XCD-locality swizzle (r11)
    const int l = threadIdx.x;
    if (l == 0) { cnt = 0; cnt2 = 0; }
    const int b = row >> 10, hw = row & 1023;
    const float* hp = hs + (size_t)b * CHW + hw;
    #pragma unroll
    for (int j = 0; j < 4; ++j) fs[l + 64 * j] = hp[(size_t)(l + 64 * j) * HW];
    __syncthreads();

    float thr = unforder(rowmin[row]) + TAU;
    #pragma unroll
    for (int j = 0; j < 4; ++j) {
        int sb = l + 64 * j;
        if (sbmin[(size_t)row * 256 + sb] <= thr) {
            int pos = atomicAdd(&cnt, 1);
            list[pos] = sb;
        }
    }
    __syncthreads();
    const int C = cnt;
    const float rn_row = rn[row];
    const uint4* gB4 = reinterpret_cast<const uint4*>(Bbf);
    u64 best = ~0ull;

    // Register-stage this lane's fs slice: k in [32*kp, 32*kp+32).
    const int cid = l >> 3, kp = l & 7;
    float4 freg4[8];
    #pragma unroll
    for (int j = 0; j < 8; ++j)
        freg4[j] = *reinterpret_cast<const float4*>(&fs[kp * 32 + 4 * j]);

    // Cooperative filter: 8 codes per pass; bv prefetched one pass ahead.
    const uint4* gBp = gB4 + (size_t)(kp >> 1) * 65536;   // this lane's plane
    const int NP = C * 4;
    uint4 bv[4];
    int code_cur = 0;
    if (NP > 0) {
        code_cur = list[0] * 32 + cid;                    // it=0 -> (it&3)==0
        const int cx = code_cur & 7, cb8 = code_cur << 3;
        #pragma unroll
        for (int j = 0; j < 4; ++j) {
            int u = ((kp & 1) << 2) + j;
            bv[j] = gBp[cb8 + (u ^ cx)];
        }
    }
    for (int it = 0; it < NP; ++it) {
        const int code = code_cur;
        uint4 nv[4];
        int code_nxt = 0;
        const bool more = (it + 1 < NP);
        if (more) {
            int it2 = it + 1;
            code_nxt = list[it2 >> 2] * 32 + (it2 & 3) * 8 + cid;
            const int cx = code_nxt & 7, cb8 = code_nxt << 3;
            #pragma unroll
            for (int j = 0; j < 4; ++j) {
                int u = ((kp & 1) << 2) + j;
                nv[j] = gBp[cb8 + (u ^ cx)];
            }
        }
        float f0 = 0.f, f1 = 0.f, f2 = 0.f, f3 = 0.f;
        #pragma unroll
        for (int j = 0; j < 4; ++j) {
            float4 fa = freg4[2 * j];
            float4 fb = freg4[2 * j + 1];
            f0 = fmaf(fa.x, bflo(bv[j].x), f0);
            f1 = fmaf(fa.y, bfhi(bv[j].x), f1);
            f2 = fmaf(fa.z, bflo(bv[j].y), f2);
            f3 = fmaf(fa.w, bfhi(bv[j].y), f3);
            f0 = fmaf(fb.x, bflo(bv[j].z), f0);
            f1 = fmaf(fb.y, bfhi(bv[j].z), f1);
            f2 = fmaf(fb.z, bflo(bv[j].w), f2);
            f3 = fmaf(fb.w, bfhi(bv[j].w), f3);
        }
        float f = (f0 + f1) + (f2 + f3);
        f += __shfl_xor(f, 1, 64);
        f += __shfl_xor(f, 2, 64);
        f += __shfl_xor(f, 4, 64);
        if (kp == 0 && -2.0f * f <= thr) {
            int pos = atomicAdd(&cnt2, 1);
            if (pos < 512) surv[pos] = code;
            else {                                 // overflow: inline exact (rare)
                u64 key = exact_key(cb, fs, rn_row, code);
                if (key < best) best = key;
            }
        }
        if (more) {
            #pragma unroll
            for (int j = 0; j < 4; ++j) bv[j] = nv[j];
            code_cur = code_nxt;
        }
    }
    __syncthreads();
    const int S = (cnt2 < 512) ? cnt2 : 512;
    for (int s0 = l; s0 < S; s0 += 64) {
        u64 key = exact_key(cb, fs, rn_row, surv[s0]);
        if (key < best) best = key;
    }
    #pragma unroll
    for (int sh = 1; sh < 64; sh <<= 1) {
        u64 o = __shfl_xor(best, sh, 64);
        if (o < best) best = o;
    }
    if (l == 0) keys[row] = best;
}

// Gather, round-19: 2048 blocks, each owns (b, 32-hw chunk, 64-c chunk).
//   r18 residual accounting: gather ~30us at 512 blocks = 2 blocks/CU = 8
//   waves/CU -> latency-bound, ~1.1 TB/s on ~34MB of traffic. 4x grid -> 32
//   waves/CU. Same coalescing; cb staging 8KB/block; index write gated to
//   c-chunk 0. Values exact: x + (qv - x) per element, unchanged formula.
__global__ __launch_bounds__(256)
void gather_kernel(const float* __restrict__ hs, const float* __restrict__ cb,
                   const u64* __restrict__ keys, float* __restrict__ out) {
    __shared__ int codes_s[32];
    __shared__ float q_s[32][65];
    __shared__ float red[4];
    const int g = blockIdx.x;            // 2048 blocks
    const int b = g >> 7;                // batch
    const int hw0 = ((g >> 2) & 31) << 5;
    const int cz = g & 3;                // 64-c chunk
    const int c0g = cz << 6;
    const int t = threadIdx.x;
    const int nbase = b * HW + hw0;

    if (t < 32) {
        int code = (int)(keys[nbase + t] & 0xFFFFFFFFULL);
        codes_s[t] = code;
        if (cz == 0) out[IDX_OFF + nbase + t] = (float)code;
    }
    __syncthreads();

    const int r = t >> 3, f4 = t & 7;    // 8 threads per row, 2 float4 each
    const float4* crow = reinterpret_cast<const float4*>(
        cb + (size_t)codes_s[r] * DIM + c0g);
    #pragma unroll
    for (int j = 0; j < 2; ++j) {
        float4 v = crow[f4 + 8 * j];
        *reinterpret_cast<float4*>(&q_s[r][4 * (f4 + 8 * j)]) = v;
    }
    __syncthreads();

    float d2 = 0.0f;
    const int hw = t & 31, cof = t >> 5;   // 8 c-lanes
    #pragma unroll 8
    for (int it = 0; it < 8; ++it) {
        int c = it * 8 + cof;              // within this 64-c chunk
        size_t off = (size_t)b * CHW + (size_t)(c0g + c) * HW + hw0 + hw;
        float x = hs[off];
        float qv = q_s[hw][c];
        out[off] = x + (qv - x);           // straight-through forward, exact formula
        float d = qv - x;
        d2 = fmaf(d, d, d2);
    }
    #pragma unroll
    for (int sh = 32; sh >= 1; sh >>= 1) d2 += __shfl_xor(d2, sh, 64);
    if ((t & 63) == 0) red[t >> 6] = d2;
    __syncthreads();
    if (t == 0) {
        float tot = red[0] + red[1] + red[2] + red[3];
        atomicAdd(out + LOSS_OFF, tot * (1.25f / 4194304.0f));  // (1+0.25)*mean
    }
}

extern "C" void kernel_launch(void* const* d_in, const int* in_sizes, int n_in,
                              void* d_out, int out_size, void* d_ws, size_t ws_size,
                              hipStream_t stream) {
    const float* hs = (const float*)d_in[0];   // (16,256,32,32) f32
    const float* cb = (const float*)d_in[1];   // (8192,256) f32
    float* out = (float*)d_out;
    char* ws = (char*)d_ws;
    u64*      keys   = (u64*)(ws + 0);
    float*    rn     = (float*)(ws + 131072);
    u32*      rowmin = (u32*)(ws + 196608);
    ushort_t* Abf    = (ushort_t*)(ws + 262144);
    ushort_t* Bbf    = (ushort_t*)(ws + 8650752);
    float*    sbmin  = (float*)(ws + 12845056);

    convert_hs<<<NROWS / 64, 128, 0, stream>>>(hs, Abf, rn, rowmin, out);
    convert_cb<<<1024, 256, 0, stream>>>(cb, Bbf);
    mfma_approx<<<dim3(NROWS / 256, KCODES / 256), 1024, 0, stream>>>(Abf, Bbf, sbmin, rowmin);
    rescore<<<NROWS, 64, 0, stream>>>(hs, cb, rn, sbmin, rowmin, keys, Bbf);
    gather_kernel<<<2048, 256, 0, stream>>>(hs, cb, keys, out);
}

// Round 9
// 250.482 us; speedup vs baseline: 1.0985x; 1.0985x over previous
//
#include <hip/hip_runtime.h>
#include <hip/hip_bf16.h>
#include <stdint.h>

#define NROWS 16384            // 16*32*32 flattened rows
#define KCODES 8192
#define DIM 256
#define HW 1024                // 32*32
#define CHW (DIM*HW)           // 262144
#define IDX_OFF 4194304        // 16*256*32*32
#define LOSS_OFF 4210688       // IDX_OFF + 16384
#define TAU 1.2e-4f            // candidate margin: grid(3.05e-5) + 2*bf16 tail + safety

typedef unsigned long long u64;
typedef unsigned int u32;
typedef unsigned short ushort_t;

using frag = __attribute__((ext_vector_type(8))) short;   // 8 bf16 (4 VGPRs)
using accf = __attribute__((ext_vector_type(4))) float;   // 4 fp32 acc

__device__ __forceinline__ u32 forder(float f) {
    u32 u = __float_as_uint(f);
    return (u & 0x80000000u) ? ~u : (u | 0x80000000u);
}
__device__ __forceinline__ float unforder(u32 v) {
    u32 u = (v & 0x80000000u) ? (v ^ 0x80000000u) : ~v;
    return __uint_as_float(u);
}
__device__ __forceinline__ ushort_t bf16bits(float v) {
    __hip_bfloat16 t = __float2bfloat16(v);   // RNE
    return *reinterpret_cast<ushort_t*>(&t);
}
__device__ __forceinline__ float bflo(u32 u) { return __uint_as_float(u << 16); }
__device__ __forceinline__ float bfhi(u32 u) { return __uint_as_float(u & 0xFFFF0000u); }
__device__ __forceinline__ void async_cp16(const uint4* gp, uint4* lp) {
    __builtin_amdgcn_global_load_lds(
        (const __attribute__((address_space(1))) unsigned int*)gp,
        (__attribute__((address_space(3))) unsigned int*)lp, 16, 0, 0);
}

// max across each 16-lane DPP row, all on the VALU pipe (no DS traffic).
__device__ __forceinline__ float max_dpp16(float v) {
    int x;
    x = __builtin_amdgcn_update_dpp(__float_as_int(v), __float_as_int(v), 0xB1, 0xF, 0xF, true);
    v = fmaxf(v, __int_as_float(x));
    x = __builtin_amdgcn_update_dpp(__float_as_int(v), __float_as_int(v), 0x4E, 0xF, 0xF, true);
    v = fmaxf(v, __int_as_float(x));
    x = __builtin_amdgcn_update_dpp(__float_as_int(v), __float_as_int(v), 0x124, 0xF, 0xF, true);
    v = fmaxf(v, __int_as_float(x));
    x = __builtin_amdgcn_update_dpp(__float_as_int(v), __float_as_int(v), 0x128, 0xF, 0xF, true);
    v = fmaxf(v, __int_as_float(x));
    return v;
}

// EXACT scoring chain (bit-identical to all passing rounds): sequential k fp32
// fmaf on fp32 cb, fl32(rn - 2*dot), key = (ordered score, code); ties -> lowest.
__device__ __forceinline__ u64 exact_key(const float* __restrict__ cb,
                                         const float* __restrict__ fs,
                                         float rn_row, int code) {
    const float4* e4 = reinterpret_cast<const float4*>(&cb[(size_t)code << 8]);
    float acc = 0.0f;
    #pragma unroll 16
    for (int kk = 0; kk < 64; ++kk) {
        float4 ev = e4[kk];
        float4 fv = *reinterpret_cast<const float4*>(&fs[kk << 2]);
        acc = fmaf(fv.x, ev.x, acc);
        acc = fmaf(fv.y, ev.y, acc);
        acc = fmaf(fv.z, ev.z, acc);
        acc = fmaf(fv.w, ev.w, acc);
    }
    float s = __fadd_rn(rn_row, -2.0f * acc);
    return ((u64)forder(s) << 32) | (u64)code;
}

// ws layout (bytes):
//   keys   u64[16384]          @ 0        (131072)
//   rn     f32[16384]          @ 131072   (65536)
//   rowmin u32[16384]          @ 196608   (65536)
//   A_bf   u16[16384*256]      @ 262144   (8388608)  PLANE-MAJOR+SWIZZLED:
//          uint4 idx = g*131072 + row*8 + ((u&7)^(row&7)), g=k-group(64k), u=k/8
//   B_bf   u16[8192*256]       @ 8650752  (4194304)  uint4 idx = g*65536 + code*8 + slot,
//          slot = u ^ (code&7)
//   sbmin  f32[16384*256]      @ 12845056 (16777216) per (row, 32-code sub) approx min

// hs -> bf16 rows (plane-major swizzled) + exact numpy-pairwise rn + inits.
// Round-18 split (verified): two half-sum chains on separate 64-thread groups;
// per-chain adds, packing, swizzled stores, rn = fadd(hs0,hs1) bit-identical.
__global__ __launch_bounds__(128)
void convert_hs(const float* __restrict__ hs, ushort_t* __restrict__ Abf,
                float* __restrict__ rn, u32* __restrict__ rowmin,
                float* __restrict__ out) {
    __shared__ uint4 tile[2][64 * 17];   // per-half tile; stride 17: bank coverage
    __shared__ float hsx[2][64];
    const int t = threadIdx.x;
    const int tr = t & 63;               // row within block
    const int h = t >> 6;                // half 0/1 (channel groups 0-127 / 128-255)
    const int row0 = blockIdx.x * 64;
    const int row = row0 + tr;
    if (h == 0) {
        rowmin[row] = 0xFFFFFFFFu;
        if (row == 0) out[LOSS_OFF] = 0.0f;
    }
    const int b = row >> 10, hw = row & 1023;
    const float* p = hs + (size_t)b * CHW + hw;
    uint4* Abf4 = reinterpret_cast<uint4*>(Abf);

    float r[8];
    for (int i = 0; i < 128; i += 8) {
        ushort_t pk[8];
        #pragma unroll
        for (int j = 0; j < 8; ++j) {
            int c = h * 128 + i + j;
            float v = p[(size_t)c * HW];       // coalesced across each group's 64 lanes
            pk[j] = bf16bits(v);
            float sq = __fmul_rn(v, v);
            r[j] = (i == 0) ? sq : __fadd_rn(r[j], sq);
        }
        uint4 o;
        o.x = (u32)pk[0] | ((u32)pk[1] << 16);
        o.y = (u32)pk[2] | ((u32)pk[3] << 16);
        o.z = (u32)pk[4] | ((u32)pk[5] << 16);
        o.w = (u32)pk[6] | ((u32)pk[7] << 16);
        tile[h][tr * 17 + (i >> 3)] = o;
    }
    float halfsum = __fadd_rn(__fadd_rn(__fadd_rn(r[0], r[1]), __fadd_rn(r[2], r[3])),
                              __fadd_rn(__fadd_rn(r[4], r[5]), __fadd_rn(r[6], r[7])));
    hsx[h][tr] = halfsum;
    __syncthreads();

    // store pass: each group writes its own half's 16 uint4 k-slots.
    #pragma unroll
    for (int pass = 0; pass < 16; ++pass) {
        int rr = pass * 4 + (tr >> 4);
        int uh = tr & 15;
        uint4 v = tile[h][rr * 17 + uh];
        int orow = row0 + rr;
        int u = h * 16 + uh;                  // global uint4 k-slot 0..31
        int g = u >> 3;
        int slot = (u & 7) ^ (orow & 7);
        Abf4[(size_t)g * 131072 + (size_t)orow * 8 + slot] = v;
    }
    if (h == 0) rn[row] = __fadd_rn(hsx[0][tr], hsx[1][tr]);
}

// codebook -> bf16, plane-major swizzled. One thread per output uint4 (coalesced).
__global__ __launch_bounds__(256)
void convert_cb(const float* __restrict__ cb, ushort_t* __restrict__ Bbf) {
    int o = blockIdx.x * 256 + threadIdx.x;        // output uint4 idx, 262144 total
    int g = o >> 16;                               // 65536 uint4 per plane
    int rem = o & 65535;
    int code = rem >> 3;
    int slot = rem & 7;
    int u = slot ^ (code & 7);                     // source uint4-in-group
    const float4* src = reinterpret_cast<const float4*>(
        cb + (size_t)code * DIM + (size_t)(g * 8 + u) * 8);
    float4 v0 = src[0], v1 = src[1];
    uint4 out_v;
    out_v.x = (u32)bf16bits(v0.x) | ((u32)bf16bits(v0.y) << 16);
    out_v.y = (u32)bf16bits(v0.z) | ((u32)bf16bits(v0.w) << 16);
    out_v.z = (u32)bf16bits(v1.x) | ((u32)bf16bits(v1.y) << 16);
    out_v.w = (u32)bf16bits(v1.z) | ((u32)bf16bits(v1.w) << 16);
    reinterpret_cast<uint4*>(Bbf)[o] = out_v;
}

// Approx GEMM, round-20: 128x128 TILE, 4 WAVES, SINGLE-BUFFERED 32 KB LDS.
//   r17's structural wall (counters): 60 VGPR + 64 AGPR = 124/wave -> 4
//   waves/SIMD cap, AND 128 KB LDS -> 1 block/CU. All 16 waves stall together
//   on every barrier's vmcnt(0) drain -> MfmaUtil stuck at 29%.
//   This round: same wave count (16/CU) but as FOUR independent 4-wave blocks
//   (LDS 32 KB/block, regs 124 -> both allow 4 blocks/CU). Each block's
//   stage->drain overlaps three other blocks' MFMA (the m97-proven operating
//   point: cross-block pipelining instead of intra-block dbuf).
//   Same fragment/swizzle algebra (row bases stay 0 mod 8), same acc[4][4],
//   same DPP epilogue -> sbmin/rowmin bit-identical.
__global__ __launch_bounds__(256, 4)
void mfma_approx(const ushort_t* __restrict__ Abf, const ushort_t* __restrict__ Bbf,
                 float* __restrict__ sbmin, u32* __restrict__ rowmin) {
    __shared__ uint4 As4[1024];   // 16 KB: [row 0..127][slot 0..7]
    __shared__ uint4 Bs4[1024];   // 16 KB: [code 0..127][slot 0..7]

    const int tid = threadIdx.x;
    const int n0 = blockIdx.x << 7;     // 128 rows per block
    const int c0 = blockIdx.y << 7;     // 128 codes per block
    const int w = tid >> 6, L = tid & 63;
    const int wr = w & 1, wc = w >> 1;  // wave tile: rows 64*wr, codes 64*wc
    const int m = L & 15, q = L >> 4;
    const uint4* gA = reinterpret_cast<const uint4*>(Abf);
    const uint4* gB = reinterpret_cast<const uint4*>(Bbf);

    accf acc[4][4];
    #pragma unroll
    for (int rt = 0; rt < 4; ++rt)
        #pragma unroll
        for (int ct = 0; ct < 4; ++ct) acc[rt][ct] = (accf){0.f, 0.f, 0.f, 0.f};

#define STAGE(gg) do {                                                        \
    _Pragma("unroll")                                                         \
    for (int r_ = 0; r_ < 4; ++r_) {                                          \
        int j_ = (r_ << 8) + tid;                                             \
        async_cp16(gA + ((size_t)(gg) * 131072 + (size_t)n0 * 8 + j_),        \
                   &As4[j_]);                                                 \
    }                                                                         \
    _Pragma("unroll")                                                         \
    for (int r_ = 0; r_ < 4; ++r_) {                                          \
        int j_ = (r_ << 8) + tid;                                             \
        async_cp16(gB + ((size_t)(gg) * 65536 + (size_t)c0 * 8 + j_),         \
                   &Bs4[j_]);                                                 \
    }                                                                         \
} while (0)

    #pragma unroll
    for (int g = 0; g < 4; ++g) {       // kc = 64*g
        STAGE(g);
        __syncthreads();                // drains stage (vmcnt 0) + publish
        #pragma unroll
        for (int ks = 0; ks < 2; ++ks) {
            const int us = ((ks << 2) + q) ^ (m & 7);
            frag a[4];
            #pragma unroll
            for (int rt = 0; rt < 4; ++rt)
                a[rt] = *reinterpret_cast<const frag*>(
                    &As4[((wr << 6) + (rt << 4) + m) * 8 + us]);
            #pragma unroll
            for (int ct = 0; ct < 4; ++ct) {
                frag bfr = *reinterpret_cast<const frag*>(
                    &Bs4[((wc << 6) + (ct << 4) + m) * 8 + us]);
                #pragma unroll
                for (int rt = 0; rt < 4; ++rt)
                    acc[rt][ct] = __builtin_amdgcn_mfma_f32_16x16x32_bf16(a[rt], bfr, acc[rt][ct], 0, 0, 0);
            }
        }
        if (g < 3) __syncthreads();     // WAR: all reads done before next STAGE
    }
#undef STAGE

    // Epilogue: subblock (32-code) mins + row min via DPP (VALU pipe only).
    // Wave covers 64 codes = 2 subblocks: p in {0,1}, ct pairs {0,1},{2,3}.
    const int cbase = (blockIdx.y << 2) + (wc << 1);
    #pragma unroll
    for (int rt = 0; rt < 4; ++rt) {
        #pragma unroll
        for (int reg = 0; reg < 4; ++reg) {
            float mx[2];
            #pragma unroll
            for (int p = 0; p < 2; ++p)
                mx[p] = fmaxf(acc[rt][2 * p][reg], acc[rt][2 * p + 1][reg]);
            #pragma unroll
            for (int p = 0; p < 2; ++p) mx[p] = max_dpp16(mx[p]);
            if (m == 0) {   // lanes 0,16,32,48 (one per 16-lane row)
                int row = n0 + (wr << 6) + (rt << 4) + (q << 2) + reg;
                float mn[2];
                #pragma unroll
                for (int p = 0; p < 2; ++p) {
                    mn[p] = -2.0f * mx[p];
                    sbmin[(size_t)row * 256 + cbase + p] = mn[p];
                }
                float m2 = fminf(mn[0], mn[1]);
                atomicMin(&rowmin[row], forder(m2));
            }
        }
    }
}

// Exact rescore (round-14 wave-cooperative filter, verified fast in r6/r7):
// 8 lanes per code, fs register-staged, survivors -> LDS list -> EXACT chain.
__global__ __launch_bounds__(64, 4)
void rescore(const float* __restrict__ hs, const float* __restrict__ cb,
             const float* __restrict__ rn, const float* __restrict__ sbmin,
             const u32* __restrict__ rowmin, u64* __restrict__ keys,
             const ushort_t* __restrict__ Bbf) {
    __shared__ __align__(16) float fs[256];
    __shared__ int list[256];
    __shared__ int surv[512];
    __shared__ int cnt, cnt2;
    const int bid = blockIdx.x;
    const int row = ((bid & 7) << 11) + (bid >> 3);   // XCD-locality swizzle (r11)
    const int l = threadIdx.x;
    if (l == 0) { cnt = 0; cnt2 = 0; }
    const int b = row >> 10, hw = row & 1023;
    const float* hp = hs + (size_t)b * CHW + hw;
    #pragma unroll
    for (int j = 0; j < 4; ++j) fs[l + 64 * j] = hp[(size_t)(l + 64 * j) * HW];
    __syncthreads();

    float thr = unforder(rowmin[row]) + TAU;
    #pragma unroll
    for (int j = 0; j < 4; ++j) {
        int sb = l + 64 * j;
        if (sbmin[(size_t)row * 256 + sb] <= thr) {
            int pos = atomicAdd(&cnt, 1);
            list[pos] = sb;
        }
    }
    __syncthreads();
    const int C = cnt;
    const float rn_row = rn[row];
    const uint4* gB4 = reinterpret_cast<const uint4*>(Bbf);
    u64 best = ~0ull;

    // Register-stage this lane's fs slice: k in [32*kp, 32*kp+32).
    const int cid = l >> 3, kp = l & 7;
    float4 freg4[8];
    #pragma unroll
    for (int j = 0; j < 8; ++j)
        freg4[j] = *reinterpret_cast<const float4*>(&fs[kp * 32 + 4 * j]);

    // Cooperative filter: 8 codes per pass (one subblock = 4 passes).
    const uint4* gBp = gB4 + (size_t)(kp >> 1) * 65536;   // this lane's plane
    for (int it = 0; it < C * 4; ++it) {
        int code = list[it >> 2] * 32 + (it & 3) * 8 + cid;
        const int cx = code & 7, cbase8 = code << 3;
        uint4 bv[4];
        #pragma unroll
        for (int j = 0; j < 4; ++j) {
            int u = ((kp & 1) << 2) + j;          // uint4-in-plane-group
            bv[j] = gBp[cbase8 + (u ^ cx)];
        }
        float f0 = 0.f, f1 = 0.f, f2 = 0.f, f3 = 0.f;
        #pragma unroll
        for (int j = 0; j < 4; ++j) {
            float4 fa = freg4[2 * j];
            float4 fb = freg4[2 * j + 1];
            f0 = fmaf(fa.x, bflo(bv[j].x), f0);
            f1 = fmaf(fa.y, bfhi(bv[j].x), f1);
            f2 = fmaf(fa.z, bflo(bv[j].y), f2);
            f3 = fmaf(fa.w, bfhi(bv[j].y), f3);
            f0 = fmaf(fb.x, bflo(bv[j].z), f0);
            f1 = fmaf(fb.y, bfhi(bv[j].z), f1);
            f2 = fmaf(fb.z, bflo(bv[j].w), f2);
            f3 = fmaf(fb.w, bfhi(bv[j].w), f3);
        }
        float f = (f0 + f1) + (f2 + f3);
        f += __shfl_xor(f, 1, 64);
        f += __shfl_xor(f, 2, 64);
        f += __shfl_xor(f, 4, 64);
        if (kp == 0 && -2.0f * f <= thr) {
            int pos = atomicAdd(&cnt2, 1);
            if (pos < 512) surv[pos] = code;
            else {                                 // overflow: inline exact (rare)
                u64 key = exact_key(cb, fs, rn_row, code);
                if (key < best) best = key;
            }
        }
    }
    __syncthreads();
    const int S = (cnt2 < 512) ? cnt2 : 512;
    for (int s0 = l; s0 < S; s0 += 64) {
        u64 key = exact_key(cb, fs, rn_row, surv[s0]);
        if (key < best) best = key;
    }
    #pragma unroll
    for (int sh = 1; sh < 64; sh <<= 1) {
        u64 o = __shfl_xor(best, sh, 64);
        if (o < best) best = o;
    }
    if (l == 0) keys[row] = best;
}

// Gather (r7-verified 512-block version): each block owns (b, 32-hw chunk) x
// all 256 c. cb rows read coalesced once into LDS; outputs coalesced.
// Values exact: x + (q - x).
__global__ __launch_bounds__(256)
void gather_kernel(const float* __restrict__ hs, const float* __restrict__ cb,
                   const u64* __restrict__ keys, float* __restrict__ out) {
    __shared__ int codes_s[32];
    __shared__ float q_s[32][257];
    __shared__ float red[4];
    const int g = blockIdx.x;
    const int b = g >> 5;
    const int hw0 = (g & 31) << 5;
    const int t = threadIdx.x;
    const int nbase = b * HW + hw0;

    if (t < 32) {
        int code = (int)(keys[nbase + t] & 0xFFFFFFFFULL);
        codes_s[t] = code;
        out[IDX_OFF + nbase + t] = (float)code;
    }
    __syncthreads();

    const int r = t >> 3, f4 = t & 7;
    const float4* crow = reinterpret_cast<const float4*>(cb + (size_t)codes_s[r] * DIM);
    #pragma unroll
    for (int j = 0; j < 8; ++j) {
        float4 v = crow[f4 + 8 * j];
        *reinterpret_cast<float4*>(&q_s[r][4 * (f4 + 8 * j)]) = v;
    }
    __syncthreads();

    float d2 = 0.0f;
    const int hw = t & 31, cof = t >> 5;   // 8 c-lanes
    #pragma unroll 8
    for (int it = 0; it < 32; ++it) {
        int c = it * 8 + cof;
        size_t off = (size_t)b * CHW + (size_t)c * HW + hw0 + hw;
        float x = hs[off];
        float qv = q_s[hw][c];
        out[off] = x + (qv - x);           // straight-through forward, exact formula
        float d = qv - x;
        d2 = fmaf(d, d, d2);
    }
    #pragma unroll
    for (int sh = 32; sh >= 1; sh >>= 1) d2 += __shfl_xor(d2, sh, 64);
    if ((t & 63) == 0) red[t >> 6] = d2;
    __syncthreads();
    if (t == 0) {
        float tot = red[0] + red[1] + red[2] + red[3];
        atomicAdd(out + LOSS_OFF, tot * (1.25f / 4194304.0f));  // (1+0.25)*mean
    }
}

extern "C" void kernel_launch(void* const* d_in, const int* in_sizes, int n_in,
                              void* d_out, int out_size, void* d_ws, size_t ws_size,
                              hipStream_t stream) {
    const float* hs = (const float*)d_in[0];   // (16,256,32,32) f32
    const float* cb = (const float*)d_in[1];   // (8192,256) f32
    float* out = (float*)d_out;
    char* ws = (char*)d_ws;
    u64*      keys   = (u64*)(ws + 0);
    float*    rn     = (float*)(ws + 131072);
    u32*      rowmin = (u32*)(ws + 196608);
    ushort_t* Abf    = (ushort_t*)(ws + 262144);
    ushort_t* Bbf    = (ushort_t*)(ws + 8650752);
    float*    sbmin  = (float*)(ws + 12845056);

    convert_hs<<<NROWS / 64, 128, 0, stream>>>(hs, Abf, rn, rowmin, out);
    convert_cb<<<1024, 256, 0, stream>>>(cb, Bbf);
    mfma_approx<<<dim3(NROWS / 128, KCODES / 128), 256, 0, stream>>>(Abf, Bbf, sbmin, rowmin);
    rescore<<<NROWS, 64, 0, stream>>>(hs, cb, rn, sbmin, rowmin, keys, Bbf);
    gather_kernel<<<512, 256, 0, stream>>>(hs, cb, keys, out);
}

// Round 10
// 243.275 us; speedup vs baseline: 1.1311x; 1.0296x over previous
//
#include <hip/hip_runtime.h>
#include <hip/hip_bf16.h>
#include <stdint.h>

#define NROWS 16384            // 16*32*32 flattened rows
#define KCODES 8192
#define DIM 256
#define HW 1024                // 32*32
#define CHW (DIM*HW)           // 262144
#define IDX_OFF 4194304        // 16*256*32*32
#define LOSS_OFF 4210688       // IDX_OFF + 16384
#define TAU 1.2e-4f            // candidate margin: grid(3.05e-5) + 2*bf16 tail + safety

typedef unsigned long long u64;
typedef unsigned int u32;
typedef unsigned short ushort_t;

using frag = __attribute__((ext_vector_type(8))) short;   // 8 bf16 (4 VGPRs)
using accf = __attribute__((ext_vector_type(4))) float;   // 4 fp32 acc

__device__ __forceinline__ u32 forder(float f) {
    u32 u = __float_as_uint(f);
    return (u & 0x80000000u) ? ~u : (u | 0x80000000u);
}
__device__ __forceinline__ float unforder(u32 v) {
    u32 u = (v & 0x80000000u) ? (v ^ 0x80000000u) : ~v;
    return __uint_as_float(u);
}
__device__ __forceinline__ ushort_t bf16bits(float v) {
    __hip_bfloat16 t = __float2bfloat16(v);   // RNE
    return *reinterpret_cast<ushort_t*>(&t);
}
__device__ __forceinline__ float bflo(u32 u) { return __uint_as_float(u << 16); }
__device__ __forceinline__ float bfhi(u32 u) { return __uint_as_float(u & 0xFFFF0000u); }
__device__ __forceinline__ void async_cp16(const uint4* gp, uint4* lp) {
    __builtin_amdgcn_global_load_lds(
        (const __attribute__((address_space(1))) unsigned int*)gp,
        (__attribute__((address_space(3))) unsigned int*)lp, 16, 0, 0);
}

// max across each 16-lane DPP row, all on the VALU pipe (no DS traffic).
__device__ __forceinline__ float max_dpp16(float v) {
    int x;
    x = __builtin_amdgcn_update_dpp(__float_as_int(v), __float_as_int(v), 0xB1, 0xF, 0xF, true);
    v = fmaxf(v, __int_as_float(x));
    x = __builtin_amdgcn_update_dpp(__float_as_int(v), __float_as_int(v), 0x4E, 0xF, 0xF, true);
    v = fmaxf(v, __int_as_float(x));
    x = __builtin_amdgcn_update_dpp(__float_as_int(v), __float_as_int(v), 0x124, 0xF, 0xF, true);
    v = fmaxf(v, __int_as_float(x));
    x = __builtin_amdgcn_update_dpp(__float_as_int(v), __float_as_int(v), 0x128, 0xF, 0xF, true);
    v = fmaxf(v, __int_as_float(x));
    return v;
}

// EXACT scoring chain (bit-identical to all passing rounds): sequential k fp32
// fmaf on fp32 cb, fl32(rn - 2*dot), key = (ordered score, code); ties -> lowest.
__device__ __forceinline__ u64 exact_key(const float* __restrict__ cb,
                                         const float* __restrict__ fs,
                                         float rn_row, int code) {
    const float4* e4 = reinterpret_cast<const float4*>(&cb[(size_t)code << 8]);
    float acc = 0.0f;
    #pragma unroll 16
    for (int kk = 0; kk < 64; ++kk) {
        float4 ev = e4[kk];
        float4 fv = *reinterpret_cast<const float4*>(&fs[kk << 2]);
        acc = fmaf(fv.x, ev.x, acc);
        acc = fmaf(fv.y, ev.y, acc);
        acc = fmaf(fv.z, ev.z, acc);
        acc = fmaf(fv.w, ev.w, acc);
    }
    float s = __fadd_rn(rn_row, -2.0f * acc);
    return ((u64)forder(s) << 32) | (u64)code;
}

// ws layout (bytes):
//   keys   u64[16384]          @ 0        (131072)
//   rn     f32[16384]          @ 131072   (65536)
//   rowmin u32[16384]          @ 196608   (65536)
//   A_bf   u16[16384*256]      @ 262144   (8388608)  PLANE-MAJOR+SWIZZLED:
//          uint4 idx = g*131072 + row*8 + ((u&7)^(row&7)), g=k-group(64k), u=k/8
//   B_bf   u16[8192*256]       @ 8650752  (4194304)  uint4 idx = g*65536 + code*8 + slot,
//          slot = u ^ (code&7)
//   sbmin  f32[16384*256]      @ 12845056 (16777216) per (row, 32-code sub) approx min
//   rowsT  f32[16384*256]      @ 29622272 (16777216) row-major exact fp32 hs rows
//          (round-21: kills rescore's 4KB-stride fs gather)

// hs -> bf16 rows (plane-major swizzled) + rowsT fp32 transpose + exact
// numpy-pairwise rn + inits. Per-row serial chain UNCHANGED (bit-exact).
__global__ __launch_bounds__(128)
void convert_hs(const float* __restrict__ hs, ushort_t* __restrict__ Abf,
                float* __restrict__ rn, u32* __restrict__ rowmin,
                float* __restrict__ out, float* __restrict__ rowsT) {
    __shared__ uint4 tile[2][64 * 17];   // per-half bf16 tile; stride 17
    __shared__ float ftile[2][64][129];  // per-half fp32 tile; stride 129 (bank-clean)
    __shared__ float hsx[2][64];
    const int t = threadIdx.x;
    const int tr = t & 63;               // row within block
    const int h = t >> 6;                // half 0/1 (channel groups 0-127 / 128-255)
    const int row0 = blockIdx.x * 64;
    const int row = row0 + tr;
    if (h == 0) {
        rowmin[row] = 0xFFFFFFFFu;
        if (row == 0) out[LOSS_OFF] = 0.0f;
    }
    const int b = row >> 10, hw = row & 1023;
    const float* p = hs + (size_t)b * CHW + hw;
    uint4* Abf4 = reinterpret_cast<uint4*>(Abf);

    float r[8];
    for (int i = 0; i < 128; i += 8) {
        ushort_t pk[8];
        #pragma unroll
        for (int j = 0; j < 8; ++j) {
            int c = h * 128 + i + j;
            float v = p[(size_t)c * HW];       // coalesced across each group's 64 lanes
            pk[j] = bf16bits(v);
            ftile[h][tr][i + j] = v;           // exact fp32 copy for rowsT
            float sq = __fmul_rn(v, v);
            r[j] = (i == 0) ? sq : __fadd_rn(r[j], sq);
        }
        uint4 o;
        o.x = (u32)pk[0] | ((u32)pk[1] << 16);
        o.y = (u32)pk[2] | ((u32)pk[3] << 16);
        o.z = (u32)pk[4] | ((u32)pk[5] << 16);
        o.w = (u32)pk[6] | ((u32)pk[7] << 16);
        tile[h][tr * 17 + (i >> 3)] = o;
    }
    float halfsum = __fadd_rn(__fadd_rn(__fadd_rn(r[0], r[1]), __fadd_rn(r[2], r[3])),
                              __fadd_rn(__fadd_rn(r[4], r[5]), __fadd_rn(r[6], r[7])));
    hsx[h][tr] = halfsum;
    __syncthreads();

    // bf16 store pass: each group writes its own half's 16 uint4 k-slots.
    #pragma unroll
    for (int pass = 0; pass < 16; ++pass) {
        int rr = pass * 4 + (tr >> 4);
        int uh = tr & 15;
        uint4 v = tile[h][rr * 17 + uh];
        int orow = row0 + rr;
        int u = h * 16 + uh;                  // global uint4 k-slot 0..31
        int g = u >> 3;
        int slot = (u & 7) ^ (orow & 7);
        Abf4[(size_t)g * 131072 + (size_t)orow * 8 + slot] = v;
    }

    // fp32 transpose store pass: coalesced 256B rows of rowsT.
    #pragma unroll 8
    for (int i = 0; i < 128; ++i) {
        int rr = i >> 1;
        int cc = ((i & 1) << 6) + tr;
        rowsT[(size_t)(row0 + rr) * 256 + (h << 7) + cc] = ftile[h][rr][cc];
    }
    if (h == 0) rn[row] = __fadd_rn(hsx[0][tr], hsx[1][tr]);
}

// codebook -> bf16, plane-major swizzled. One thread per output uint4 (coalesced).
__global__ __launch_bounds__(256)
void convert_cb(const float* __restrict__ cb, ushort_t* __restrict__ Bbf) {
    int o = blockIdx.x * 256 + threadIdx.x;        // output uint4 idx, 262144 total
    int g = o >> 16;                               // 65536 uint4 per plane
    int rem = o & 65535;
    int code = rem >> 3;
    int slot = rem & 7;
    int u = slot ^ (code & 7);                     // source uint4-in-group
    const float4* src = reinterpret_cast<const float4*>(
        cb + (size_t)code * DIM + (size_t)(g * 8 + u) * 8);
    float4 v0 = src[0], v1 = src[1];
    uint4 out_v;
    out_v.x = (u32)bf16bits(v0.x) | ((u32)bf16bits(v0.y) << 16);
    out_v.y = (u32)bf16bits(v0.z) | ((u32)bf16bits(v0.w) << 16);
    out_v.z = (u32)bf16bits(v1.x) | ((u32)bf16bits(v1.y) << 16);
    out_v.w = (u32)bf16bits(v1.z) | ((u32)bf16bits(v1.w) << 16);
    reinterpret_cast<uint4*>(Bbf)[o] = out_v;
}

// Approx GEMM (round-20, best measured 90.7us): 128x128 tile, 4 waves,
// single-buffered 32 KB LDS, 4 blocks/CU cross-block pipelining, DPP epilogue.
__global__ __launch_bounds__(256, 4)
void mfma_approx(const ushort_t* __restrict__ Abf, const ushort_t* __restrict__ Bbf,
                 float* __restrict__ sbmin, u32* __restrict__ rowmin) {
    __shared__ uint4 As4[1024];   // 16 KB: [row 0..127][slot 0..7]
    __shared__ uint4 Bs4[1024];   // 16 KB: [code 0..127][slot 0..7]

    const int tid = threadIdx.x;
    const int n0 = blockIdx.x << 7;     // 128 rows per block
    const int c0 = blockIdx.y << 7;     // 128 codes per block
    const int w = tid >> 6, L = tid & 63;
    const int wr = w & 1, wc = w >> 1;  // wave tile: rows 64*wr, codes 64*wc
    const int m = L & 15, q = L >> 4;
    const uint4* gA = reinterpret_cast<const uint4*>(Abf);
    const uint4* gB = reinterpret_cast<const uint4*>(Bbf);

    accf acc[4][4];
    #pragma unroll
    for (int rt = 0; rt < 4; ++rt)
        #pragma unroll
        for (int ct = 0; ct < 4; ++ct) acc[rt][ct] = (accf){0.f, 0.f, 0.f, 0.f};

#define STAGE(gg) do {                                                        \
    _Pragma("unroll")                                                         \
    for (int r_ = 0; r_ < 4; ++r_) {                                          \
        int j_ = (r_ << 8) + tid;                                             \
        async_cp16(gA + ((size_t)(gg) * 131072 + (size_t)n0 * 8 + j_),        \
                   &As4[j_]);                                                 \
    }                                                                         \
    _Pragma("unroll")                                                         \
    for (int r_ = 0; r_ < 4; ++r_) {                                          \
        int j_ = (r_ << 8) + tid;                                             \
        async_cp16(gB + ((size_t)(gg) * 65536 + (size_t)c0 * 8 + j_),         \
                   &Bs4[j_]);                                                 \
    }                                                                         \
} while (0)

    #pragma unroll
    for (int g = 0; g < 4; ++g) {       // kc = 64*g
        STAGE(g);
        __syncthreads();                // drains stage (vmcnt 0) + publish
        #pragma unroll
        for (int ks = 0; ks < 2; ++ks) {
            const int us = ((ks << 2) + q) ^ (m & 7);
            frag a[4];
            #pragma unroll
            for (int rt = 0; rt < 4; ++rt)
                a[rt] = *reinterpret_cast<const frag*>(
                    &As4[((wr << 6) + (rt << 4) + m) * 8 + us]);
            #pragma unroll
            for (int ct = 0; ct < 4; ++ct) {
                frag bfr = *reinterpret_cast<const frag*>(
                    &Bs4[((wc << 6) + (ct << 4) + m) * 8 + us]);
                #pragma unroll
                for (int rt = 0; rt < 4; ++rt)
                    acc[rt][ct] = __builtin_amdgcn_mfma_f32_16x16x32_bf16(a[rt], bfr, acc[rt][ct], 0, 0, 0);
            }
        }
        if (g < 3) __syncthreads();     // WAR: all reads done before next STAGE
    }
#undef STAGE

    // Epilogue: subblock (32-code) mins + row min via DPP (VALU pipe only).
    // Wave covers 64 codes = 2 subblocks: p in {0,1}, ct pairs {0,1},{2,3}.
    const int cbase = (blockIdx.y << 2) + (wc << 1);
    #pragma unroll
    for (int rt = 0; rt < 4; ++rt) {
        #pragma unroll
        for (int reg = 0; reg < 4; ++reg) {
            float mx[2];
            #pragma unroll
            for (int p = 0; p < 2; ++p)
                mx[p] = fmaxf(acc[rt][2 * p][reg], acc[rt][2 * p + 1][reg]);
            #pragma unroll
            for (int p = 0; p < 2; ++p) mx[p] = max_dpp16(mx[p]);
            if (m == 0) {   // lanes 0,16,32,48 (one per 16-lane row)
                int row = n0 + (wr << 6) + (rt << 4) + (q << 2) + reg;
                float mn[2];
                #pragma unroll
                for (int p = 0; p < 2; ++p) {
                    mn[p] = -2.0f * mx[p];
                    sbmin[(size_t)row * 256 + cbase + p] = mn[p];
                }
                float m2 = fminf(mn[0], mn[1]);
                atomicMin(&rowmin[row], forder(m2));
            }
        }
    }
}

// Exact rescore (round-14 wave-cooperative filter; round-21: fs-fill reads the
// coalesced rowsT copy — one float4 per lane — instead of the 4KB-stride hs
// gather that was 256 scattered lines/block). fs values bit-identical fp32.
__global__ __launch_bounds__(64, 4)
void rescore(const float* __restrict__ rowsT, const float* __restrict__ cb,
             const float* __restrict__ rn, const float* __restrict__ sbmin,
             const u32* __restrict__ rowmin, u64* __restrict__ keys,
             const ushort_t* __restrict__ Bbf) {
    __shared__ __align__(16) float fs[256];
    __shared__ int list[256];
    __shared__ int surv[512];
    __shared__ int cnt, cnt2;
    const int bid = blockIdx.x;
    const int row = ((bid & 7) << 11) + (bid >> 3);   // XCD-locality swizzle (r11)
    const int l = threadIdx.x;
    if (l == 0) { cnt = 0; cnt2 = 0; }
    const float4* rT = reinterpret_cast<const float4*>(rowsT + ((size_t)row << 8));
    *reinterpret_cast<float4*>(&fs[l << 2]) = rT[l];   // 64 lanes x 16B = full row
    __syncthreads();

    float thr = unforder(rowmin[row]) + TAU;
    #pragma unroll
    for (int j = 0; j < 4; ++j) {
        int sb = l + 64 * j;
        if (sbmin[(size_t)row * 256 + sb] <= thr) {
            int pos = atomicAdd(&cnt, 1);
            list[pos] = sb;
        }
    }
    __syncthreads();
    const int C = cnt;
    const float rn_row = rn[row];
    const uint4* gB4 = reinterpret_cast<const uint4*>(Bbf);
    u64 best = ~0ull;

    // Register-stage this lane's fs slice: k in [32*kp, 32*kp+32).
    const int cid = l >> 3, kp = l & 7;
    float4 freg4[8];
    #pragma unroll
    for (int j = 0; j < 8; ++j)
        freg4[j] = *reinterpret_cast<const float4*>(&fs[kp * 32 + 4 * j]);

    // Cooperative filter: 8 codes per pass (one subblock = 4 passes).
    const uint4* gBp = gB4 + (size_t)(kp >> 1) * 65536;   // this lane's plane
    for (int it = 0; it < C * 4; ++it) {
        int code = list[it >> 2] * 32 + (it & 3) * 8 + cid;
        const int cx = code & 7, cbase8 = code << 3;
        uint4 bv[4];
        #pragma unroll
        for (int j = 0; j < 4; ++j) {
            int u = ((kp & 1) << 2) + j;          // uint4-in-plane-group
            bv[j] = gBp[cbase8 + (u ^ cx)];
        }
        float f0 = 0.f, f1 = 0.f, f2 = 0.f, f3 = 0.f;
        #pragma unroll
        for (int j = 0; j < 4; ++j) {
            float4 fa = freg4[2 * j];
            float4 fb = freg4[2 * j + 1];
            f0 = fmaf(fa.x, bflo(bv[j].x), f0);
            f1 = fmaf(fa.y, bfhi(bv[j].x), f1);
            f2 = fmaf(fa.z, bflo(bv[j].y), f2);
            f3 = fmaf(fa.w, bfhi(bv[j].y), f3);
            f0 = fmaf(fb.x, bflo(bv[j].z), f0);
            f1 = fmaf(fb.y, bfhi(bv[j].z), f1);
            f2 = fmaf(fb.z, bflo(bv[j].w), f2);
            f3 = fmaf(fb.w, bfhi(bv[j].w), f3);
        }
        float f = (f0 + f1) + (f2 + f3);
        f += __shfl_xor(f, 1, 64);
        f += __shfl_xor(f, 2, 64);
        f += __shfl_xor(f, 4, 64);
        if (kp == 0 && -2.0f * f <= thr) {
            int pos = atomicAdd(&cnt2, 1);
            if (pos < 512) surv[pos] = code;
            else {                                 // overflow: inline exact (rare)
                u64 key = exact_key(cb, fs, rn_row, code);
                if (key < best) best = key;
            }
        }
    }
    __syncthreads();
    const int S = (cnt2 < 512) ? cnt2 : 512;
    for (int s0 = l; s0 < S; s0 += 64) {
        u64 key = exact_key(cb, fs, rn_row, surv[s0]);
        if (key < best) best = key;
    }
    #pragma unroll
    for (int sh = 1; sh < 64; sh <<= 1) {
        u64 o = __shfl_xor(best, sh, 64);
        if (o < best) best = o;
    }
    if (l == 0) keys[row] = best;
}

// Gather (r7-verified 512-block version): each block owns (b, 32-hw chunk) x
// all 256 c. cb rows read coalesced once into LDS; outputs coalesced.
// Values exact: x + (q - x).
__global__ __launch_bounds__(256)
void gather_kernel(const float* __restrict__ hs, const float* __restrict__ cb,
                   const u64* __restrict__ keys, float* __restrict__ out) {
    __shared__ int codes_s[32];
    __shared__ float q_s[32][257];
    __shared__ float red[4];
    const int g = blockIdx.x;
    const int b = g >> 5;
    const int hw0 = (g & 31) << 5;
    const int t = threadIdx.x;
    const int nbase = b * HW + hw0;

    if (t < 32) {
        int code = (int)(keys[nbase + t] & 0xFFFFFFFFULL);
        codes_s[t] = code;
        out[IDX_OFF + nbase + t] = (float)code;
    }
    __syncthreads();

    const int r = t >> 3, f4 = t & 7;
    const float4* crow = reinterpret_cast<const float4*>(cb + (size_t)codes_s[r] * DIM);
    #pragma unroll
    for (int j = 0; j < 8; ++j) {
        float4 v = crow[f4 + 8 * j];
        *reinterpret_cast<float4*>(&q_s[r][4 * (f4 + 8 * j)]) = v;
    }
    __syncthreads();

    float d2 = 0.0f;
    const int hw = t & 31, cof = t >> 5;   // 8 c-lanes
    #pragma unroll 8
    for (int it = 0; it < 32; ++it) {
        int c = it * 8 + cof;
        size_t off = (size_t)b * CHW + (size_t)c * HW + hw0 + hw;
        float x = hs[off];
        float qv = q_s[hw][c];
        out[off] = x + (qv - x);           // straight-through forward, exact formula
        float d = qv - x;
        d2 = fmaf(d, d, d2);
    }
    #pragma unroll
    for (int sh = 32; sh >= 1; sh >>= 1) d2 += __shfl_xor(d2, sh, 64);
    if ((t & 63) == 0) red[t >> 6] = d2;
    __syncthreads();
    if (t == 0) {
        float tot = red[0] + red[1] + red[2] + red[3];
        atomicAdd(out + LOSS_OFF, tot * (1.25f / 4194304.0f));  // (1+0.25)*mean
    }
}

extern "C" void kernel_launch(void* const* d_in, const int* in_sizes, int n_in,
                              void* d_out, int out_size, void* d_ws, size_t ws_size,
                              hipStream_t stream) {
    const float* hs = (const float*)d_in[0];   // (16,256,32,32) f32
    const float* cb = (const float*)d_in[1];   // (8192,256) f32
    float* out = (float*)d_out;
    char* ws = (char*)d_ws;
    u64*      keys   = (u64*)(ws + 0);
    float*    rn     = (float*)(ws + 131072);
    u32*      rowmin = (u32*)(ws + 196608);
    ushort_t* Abf    = (ushort_t*)(ws + 262144);
    ushort_t* Bbf    = (ushort_t*)(ws + 8650752);
    float*    sbmin  = (float*)(ws + 12845056);
    float*    rowsT  = (float*)(ws + 29622272);

    convert_hs<<<NROWS / 64, 128, 0, stream>>>(hs, Abf, rn, rowmin, out, rowsT);
    convert_cb<<<1024, 256, 0, stream>>>(cb, Bbf);
    mfma_approx<<<dim3(NROWS / 128, KCODES / 128), 256, 0, stream>>>(Abf, Bbf, sbmin, rowmin);
    rescore<<<NROWS, 64, 0, stream>>>(rowsT, cb, rn, sbmin, rowmin, keys, Bbf);
    gather_kernel<<<512, 256, 0, stream>>>(hs, cb, keys, out);
}